// Round 5
// baseline (1849.290 us; speedup 1.0000x reference)
//
#include <hip/hip_runtime.h>
#include <math.h>

#define NN 100000
#define HID 128
#define EPSV 1e-5f

typedef short bf16x8 __attribute__((ext_vector_type(8)));
typedef float f32x4 __attribute__((ext_vector_type(4)));
typedef unsigned short u16;

__device__ __forceinline__ u16 f2b(float f) {       // f32 -> bf16 RNE
  unsigned u = __builtin_bit_cast(unsigned, f);
  u += 0x7FFFu + ((u >> 16) & 1u);
  return (u16)(u >> 16);
}
__device__ __forceinline__ float b2f(u16 h) {
  unsigned u = ((unsigned)h) << 16;
  return __builtin_bit_cast(float, u);
}

#define AS1(p) ((__attribute__((address_space(1))) void*)(p))
#define AS3(p) ((__attribute__((address_space(3))) void*)(p))

// ---------------- utility kernels ----------------

static __global__ void k_zero(float* __restrict__ p, int n) {
  int i = blockIdx.x * blockDim.x + threadIdx.x;
  if (i < n) p[i] = 0.f;
}

static __global__ void k_zero_i(int* __restrict__ p, int n) {
  int i = blockIdx.x * blockDim.x + threadIdx.x;
  if (i < n) p[i] = 0;
}

static __global__ void k_deg(const int* __restrict__ src, const int* __restrict__ dst,
                             int E, float* __restrict__ outdeg, float* __restrict__ indeg) {
  int e = blockIdx.x * blockDim.x + threadIdx.x;
  if (e < E) {
    atomicAdd(&outdeg[src[e]], 1.f);
    atomicAdd(&indeg[dst[e]], 1.f);
  }
}

static __global__ void k_counts(const float* __restrict__ indegRaw, int* __restrict__ counts, int n3) {
  int i = blockIdx.x * blockDim.x + threadIdx.x;
  if (i < n3) counts[i] = (int)indegRaw[i];
  else if (i == n3) counts[i] = 0;
}

static __global__ void k_rsqrt_clip(float* __restrict__ p, int n) {
  int i = blockIdx.x * blockDim.x + threadIdx.x;
  if (i < n) p[i] = rsqrtf(fmaxf(p[i], 1.f));
}

// ---------------- exclusive scan (two-level) ----------------
static __global__ void k_scan1(const int* __restrict__ in, int* __restrict__ out,
                               int* __restrict__ aux, int n) {
  __shared__ int s[256];
  int t = threadIdx.x, i = blockIdx.x * 256 + t;
  int v = (i < n) ? in[i] : 0;
  s[t] = v; __syncthreads();
#pragma unroll
  for (int d = 1; d < 256; d <<= 1) {
    int x = (t >= d) ? s[t - d] : 0;
    __syncthreads();
    s[t] += x;
    __syncthreads();
  }
  if (i < n) out[i] = s[t] - v;
  if (t == 255) aux[blockIdx.x] = s[255];
}

static __global__ void k_scan2(int* __restrict__ aux, int nb) {
  __shared__ int s[256];
  __shared__ int carry;
  int t = threadIdx.x;
  if (t == 0) carry = 0;
  __syncthreads();
  for (int base = 0; base < nb; base += 256) {
    int i = base + t;
    int v = (i < nb) ? aux[i] : 0;
    s[t] = v; __syncthreads();
#pragma unroll
    for (int d = 1; d < 256; d <<= 1) {
      int x = (t >= d) ? s[t - d] : 0;
      __syncthreads();
      s[t] += x;
      __syncthreads();
    }
    int excl = s[t] - v + carry;
    if (i < nb) aux[i] = excl;
    int tot = s[255];
    __syncthreads();
    if (t == 0) carry += tot;
    __syncthreads();
  }
}

static __global__ void k_scan3(int* __restrict__ out, const int* __restrict__ aux, int n) {
  int i = blockIdx.x * 256 + threadIdx.x;
  if (i < n) out[i] += aux[blockIdx.x];
}

static __global__ void k_fill(const int* __restrict__ src, const int* __restrict__ dst, int E,
                              const int* __restrict__ off, int* __restrict__ cur,
                              int rbase, int* __restrict__ srt) {
  int e = blockIdx.x * blockDim.x + threadIdx.x;
  if (e < E) {
    int d = dst[e];
    int p = off[rbase + d] + atomicAdd(&cur[rbase + d], 1);
    srt[p] = src[e];
  }
}

// W [3][K][128] f32 -> Wt [3*128][K] bf16 (row = rel*128 + outcol)
static __global__ void k_cvt_w(const float* __restrict__ W, u16* __restrict__ Wt, int K) {
  int i = blockIdx.x * blockDim.x + threadIdx.x;
  int tot = 3 * K * 128;
  if (i < tot) {
    int rel = i / (K * 128);
    int rem = i - rel * K * 128;
    int k = rem >> 7;
    int c = rem & 127;
    Wt[((size_t)rel * 128 + c) * K + k] = f2b(W[i]);
  }
}

// ---------------- fused MFMA GEMM: Y[row, c] = sout[c>>7][row] * (A[row,:] @ Wt[c,:]) ----------------
// One block = BM 128 x BN 384 (all 3 relations share the A tile). 512 threads = 8 waves (2m x 4n),
// wave tile 64x96 (4x6 fragments). A: f32 reg-staged (layer 0) or global_load_lds (layer 1);
// B: always global_load_lds. LDS fragment-major, double-buffered (64 KB).
template<int K, bool ABF16>
__global__ __launch_bounds__(512)
void k_gemm_mfma(const void* __restrict__ Av,
                 const u16* __restrict__ Wt,    // [384][K] bf16
                 const float* __restrict__ sout,// [3][NN]
                 u16* __restrict__ Y,           // [M][384] bf16
                 int M)
{
  __shared__ u16 Al[2][4096];   // 2 x 8 KB  : 128 rows x 32 k
  __shared__ u16 Bl[2][12288];  // 2 x 24 KB : 384 rows x 32 k

  const int row0 = blockIdx.x * 128;
  const int t    = threadIdx.x;
  const int lane = t & 63;
  const int w    = t >> 6;          // 0..7
  const int wm   = w >> 2;          // 0..1
  const int wn   = w & 3;           // 0..3
  const int l15  = lane & 15, l4 = lane >> 4;
  const int kl   = l4 * 8;
  const int nk   = K / 32;

  // A staging source: this wave stages fragment-block fm = w (rows row0+w*16 .. +16)
  int ar = row0 + w * 16 + l15;  if (ar >= M) ar = M - 1;   // clamped dup read
  // B staging: this wave stages fragment-blocks fn = w*3 + {0,1,2}
  const u16* gb0 = Wt + (size_t)(w * 48 +      l15) * K + kl;
  const u16* gb1 = Wt + (size_t)(w * 48 + 16 + l15) * K + kl;
  const u16* gb2 = Wt + (size_t)(w * 48 + 32 + l15) * K + kl;

  const u16*   ga = nullptr;
  const float* pa = nullptr;
  if constexpr (ABF16) ga = (const u16*)Av + (size_t)ar * K + kl;
  else                 pa = (const float*)Av + (size_t)ar * K + kl;

  f32x4 acc[4][6];
#pragma unroll
  for (int m = 0; m < 4; ++m)
#pragma unroll
    for (int n = 0; n < 6; ++n) acc[m][n] = (f32x4){0.f, 0.f, 0.f, 0.f};

  // ---- prologue: stage k=0 into buffer 0 ----
  __builtin_amdgcn_global_load_lds(AS1(gb0), AS3(&Bl[0][(w * 3 + 0) * 512]), 16, 0, 0);
  __builtin_amdgcn_global_load_lds(AS1(gb1), AS3(&Bl[0][(w * 3 + 1) * 512]), 16, 0, 0);
  __builtin_amdgcn_global_load_lds(AS1(gb2), AS3(&Bl[0][(w * 3 + 2) * 512]), 16, 0, 0);
  if constexpr (ABF16) {
    __builtin_amdgcn_global_load_lds(AS1(ga), AS3(&Al[0][w * 512]), 16, 0, 0);
  } else {
    float4 v0 = *(const float4*)(pa);
    float4 v1 = *(const float4*)(pa + 4);
    union { bf16x8 v; u16 u[8]; } q;
    q.u[0] = f2b(v0.x); q.u[1] = f2b(v0.y); q.u[2] = f2b(v0.z); q.u[3] = f2b(v0.w);
    q.u[4] = f2b(v1.x); q.u[5] = f2b(v1.y); q.u[6] = f2b(v1.z); q.u[7] = f2b(v1.w);
    *(bf16x8*)&Al[0][w * 512 + lane * 8] = q.v;
  }
  __syncthreads();

#pragma unroll 2
  for (int k = 0; k < nk; ++k) {
    const int cur = k & 1, nxt = cur ^ 1;
    const int k1 = (k + 1) * 32;

    // fragments for this step
    bf16x8 a[4], b[6];
#pragma unroll
    for (int m = 0; m < 4; ++m) a[m] = *(const bf16x8*)&Al[cur][(wm * 4 + m) * 512 + lane * 8];
#pragma unroll
    for (int n = 0; n < 6; ++n) b[n] = *(const bf16x8*)&Bl[cur][(wn * 6 + n) * 512 + lane * 8];

    // issue next-step staging early (latency hidden under the MFMA cluster)
    float4 v0, v1;
    if (k + 1 < nk) {
      __builtin_amdgcn_global_load_lds(AS1(gb0 + k1), AS3(&Bl[nxt][(w * 3 + 0) * 512]), 16, 0, 0);
      __builtin_amdgcn_global_load_lds(AS1(gb1 + k1), AS3(&Bl[nxt][(w * 3 + 1) * 512]), 16, 0, 0);
      __builtin_amdgcn_global_load_lds(AS1(gb2 + k1), AS3(&Bl[nxt][(w * 3 + 2) * 512]), 16, 0, 0);
      if constexpr (ABF16) {
        __builtin_amdgcn_global_load_lds(AS1(ga + k1), AS3(&Al[nxt][w * 512]), 16, 0, 0);
      } else {
        v0 = *(const float4*)(pa + k1);
        v1 = *(const float4*)(pa + k1 + 4);
      }
    }

#pragma unroll
    for (int m = 0; m < 4; ++m)
#pragma unroll
      for (int n = 0; n < 6; ++n)
        acc[m][n] = __builtin_amdgcn_mfma_f32_16x16x32_bf16(a[m], b[n], acc[m][n], 0, 0, 0);

    if constexpr (!ABF16) {
      if (k + 1 < nk) {
        union { bf16x8 v; u16 u[8]; } q;
        q.u[0] = f2b(v0.x); q.u[1] = f2b(v0.y); q.u[2] = f2b(v0.z); q.u[3] = f2b(v0.w);
        q.u[4] = f2b(v1.x); q.u[5] = f2b(v1.y); q.u[6] = f2b(v1.z); q.u[7] = f2b(v1.w);
        *(bf16x8*)&Al[nxt][w * 512 + lane * 8] = q.v;
      }
    }
    __syncthreads();
  }

  // epilogue: C layout col=lane&15, row=(lane>>4)*4+reg
#pragma unroll
  for (int m = 0; m < 4; ++m) {
    const int rb = row0 + wm * 64 + m * 16 + l4 * 4;
#pragma unroll
    for (int j = 0; j < 4; ++j) {
      const int row = rb + j;
      if (row < M) {
        u16* yrow = Y + (size_t)row * 384;
#pragma unroll
        for (int n = 0; n < 6; ++n) {
          const int c = wn * 96 + n * 16;          // global output column of this frag
          const float sc = sout[(size_t)(c >> 7) * NN + row];
          yrow[c + l15] = f2b(acc[m][n][j] * sc);
        }
      }
    }
  }
}

// ---------------- CSR gather ----------------
static __global__ __launch_bounds__(256)
void k_gather(const int* __restrict__ off, const int* __restrict__ srt,
              const float* __restrict__ sin_, const u16* __restrict__ Y,
              const float* __restrict__ b, float* __restrict__ acc)
{
  int d = blockIdx.x * 4 + (threadIdx.x >> 6);
  if (d >= NN) return;
  int c = (threadIdx.x & 63) * 2;
  float v0 = b[c]     + b[128 + c]     + b[256 + c];
  float v1 = b[c + 1] + b[128 + c + 1] + b[256 + c + 1];
#pragma unroll
  for (int r = 0; r < 3; ++r) {
    int base = r * NN + d;
    int j0 = off[base], j1 = off[base + 1];
    float p0 = 0.f, p1 = 0.f;
    for (int j = j0; j < j1; ++j) {
      int s = srt[j];
      unsigned u = *(const unsigned*)&Y[(size_t)s * 384 + r * 128 + c];
      p0 += b2f((u16)(u & 0xFFFFu));
      p1 += b2f((u16)(u >> 16));
    }
    float sc = sin_[base];
    v0 += p0 * sc;
    v1 += p1 * sc;
  }
  *(float2*)&acc[(size_t)d * 128 + c] = make_float2(v0, v1);
}

// ---------------- FC (128x128) + bias + ReLU ----------------
static __global__ __launch_bounds__(256)
void k_fc_relu(const float* __restrict__ X, int M,
               const float* __restrict__ Wfc, const float* __restrict__ bfc,
               float* __restrict__ Z)
{
  __shared__ float Ws[128 * 64];
  __shared__ float xs[4][128];
  const int j0 = blockIdx.y * 64;
  const int t = threadIdx.x;

  for (int i = t; i < 128 * 64; i += 256) {
    int k = i >> 6, c = i & 63;
    Ws[i] = Wfc[k * 128 + j0 + c];
  }
  const int rl = t >> 6;
  const int c  = t & 63;
  const float bb = bfc[j0 + c];
  __syncthreads();

  for (int row0 = blockIdx.x * 4; row0 < M; row0 += gridDim.x * 4) {
    int row = row0 + rl;
    if (row < M) {
      xs[rl][c]      = X[(size_t)row * 128 + c];
      xs[rl][c + 64] = X[(size_t)row * 128 + c + 64];
    }
    __syncthreads();
    if (row < M) {
      float acc = bb;
#pragma unroll
      for (int k = 0; k < 128; ++k)
        acc = fmaf(xs[rl][k], Ws[k * 64 + c], acc);
      Z[(size_t)row * 128 + j0 + c] = fmaxf(acc, 0.f);
    }
    __syncthreads();
  }
}

// ---------------- BatchNorm ----------------
static __global__ void k_bn_stats(const float* __restrict__ Z, int M, float* __restrict__ stats) {
  int col = threadIdx.x;  // 128
  float s = 0.f, s2 = 0.f;
  for (int row = blockIdx.x; row < M; row += gridDim.x) {
    float v = Z[(size_t)row * 128 + col];
    s += v;
    s2 += v * v;
  }
  atomicAdd(&stats[col], s);
  atomicAdd(&stats[128 + col], s2);
}

static __global__ void k_bn_finalize(const float* __restrict__ stats, int M,
                                     const float* __restrict__ g, const float* __restrict__ beta,
                                     float* __restrict__ ab) {
  int j = threadIdx.x;  // 128
  float m  = stats[j] / (float)M;
  float v  = stats[128 + j] / (float)M - m * m;
  float inv = rsqrtf(v + EPSV) * g[j];
  ab[j]       = inv;
  ab[128 + j] = beta[j] - m * inv;
}

template<bool OUT_BF16>
static __global__ void k_bn_apply(const float* __restrict__ Z, const float* __restrict__ ab,
                                  void* __restrict__ out, int n) {
  int i = blockIdx.x * blockDim.x + threadIdx.x;
  if (i < n) {
    int j = i & 127;
    float v = Z[i] * ab[j] + ab[128 + j];
    if constexpr (OUT_BF16) ((u16*)out)[i] = f2b(v);
    else                    ((float*)out)[i] = v;
  }
}

// ---------------- host-side layer driver ----------------

template<int K, bool ABF16, bool OUT_BF16>
static void run_layer(const void* X,
                      const u16* Wt, const float* b,
                      const float* fcW, const float* fcb,
                      const float* g, const float* beta,
                      const int* off, const int* srt,
                      float* sOut, float* sIn, u16* Y, float* Z, float* acc,
                      float* stats, float* ab, void* out, hipStream_t stream)
{
  const int NT = (NN + 127) / 128;
  k_gemm_mfma<K, ABF16><<<NT, 512, 0, stream>>>(X, Wt, sOut, Y, NN);

  k_gather<<<(NN + 3) / 4, 256, 0, stream>>>(off, srt, sIn, Y, b, acc);

  k_fc_relu<<<dim3(2048, 2), 256, 0, stream>>>(acc, NN, fcW, fcb, Z);

  k_zero<<<1, 256, 0, stream>>>(stats, 256);
  k_bn_stats<<<1024, 128, 0, stream>>>(Z, NN, stats);
  k_bn_finalize<<<1, 128, 0, stream>>>(stats, NN, g, beta, ab);
  k_bn_apply<OUT_BF16><<<(NN * HID + 255) / 256, 256, 0, stream>>>(Z, ab, out, NN * HID);
}

extern "C" void kernel_launch(void* const* d_in, const int* in_sizes, int n_in,
                              void* d_out, int out_size, void* d_ws, size_t ws_size,
                              hipStream_t stream)
{
  const float* x    = (const float*)d_in[0];
  const int*   seq  = (const int*)d_in[1];
  const int*   knn  = (const int*)d_in[2];
  const int*   dis  = (const int*)d_in[3];
  const float* W0   = (const float*)d_in[4];
  const float* b0   = (const float*)d_in[5];
  const float* fcW0 = (const float*)d_in[6];
  const float* fcb0 = (const float*)d_in[7];
  const float* g0   = (const float*)d_in[8];
  const float* be0  = (const float*)d_in[9];
  const float* W1   = (const float*)d_in[10];
  const float* b1   = (const float*)d_in[11];
  const float* fcW1 = (const float*)d_in[12];
  const float* fcb1 = (const float*)d_in[13];
  const float* g1   = (const float*)d_in[14];
  const float* be1  = (const float*)d_in[15];

  const int E[3] = { in_sizes[1] / 2, in_sizes[2] / 2, in_sizes[3] / 2 };
  const int* srcs[3] = { seq, knn, dis };

  const size_t N = NN;
  const int M3 = 3 * NN;

  float* ws    = (float*)d_ws;
  float* sOut  = ws;                        // 3N
  float* sIn   = sOut + 3 * N;              // 3N
  float* acc   = sIn + 3 * N;               // N*128
  float* stats = acc + N * 128;             // 256
  float* ab    = stats + 256;               // 256
  u16*   Y     = (u16*)(ab + 256);          // N*384 bf16 (Z aliases: Y dead after gather)
  float* Z     = (float*)Y;                 // N*128 f32
  u16*   h16   = Y + N * 384;               // N*128 bf16
  u16*   Wt0   = h16 + N * 128;             // 3*128*1280
  u16*   Wt1   = Wt0 + 3 * 128 * 1280;      // 3*128*128
  int*   counts= (int*)(Wt1 + 3 * 128 * 128);
  int*   off   = counts + (M3 + 1);
  int*   aux   = off + (M3 + 1);
  int*   cur   = aux + 1536;
  int*   srt   = cur + M3;                  // ETOT ints

  // weight transpose+convert
  k_cvt_w<<<(3 * 1280 * 128 + 255) / 256, 256, 0, stream>>>(W0, Wt0, 1280);
  k_cvt_w<<<(3 * 128 * 128 + 255) / 256, 256, 0, stream>>>(W1, Wt1, 128);

  // degrees
  k_zero<<<(6 * NN + 255) / 256, 256, 0, stream>>>(sOut, 6 * NN);
  for (int r = 0; r < 3; ++r) {
    k_deg<<<(E[r] + 255) / 256, 256, 0, stream>>>(
        srcs[r], srcs[r] + E[r], E[r], sOut + (size_t)r * N, sIn + (size_t)r * N);
  }
  k_counts<<<(M3 + 1 + 255) / 256, 256, 0, stream>>>(sIn, counts, M3);
  k_rsqrt_clip<<<(6 * NN + 255) / 256, 256, 0, stream>>>(sOut, 6 * NN);

  // CSR: exclusive scan of counts[M3+1] -> off
  const int nsc = M3 + 1;
  const int nb  = (nsc + 255) / 256;
  k_scan1<<<nb, 256, 0, stream>>>(counts, off, aux, nsc);
  k_scan2<<<1, 256, 0, stream>>>(aux, nb);
  k_scan3<<<nb, 256, 0, stream>>>(off, aux, nsc);

  k_zero_i<<<(M3 + 255) / 256, 256, 0, stream>>>(cur, M3);
  for (int r = 0; r < 3; ++r) {
    k_fill<<<(E[r] + 255) / 256, 256, 0, stream>>>(
        srcs[r], srcs[r] + E[r], E[r], off, cur, r * NN, srt);
  }

  // layer 0: x f32 [N,1280] -> h16 bf16 [N,128]
  run_layer<1280, false, true>(x, Wt0, b0, fcW0, fcb0, g0, be0, off, srt,
                               sOut, sIn, Y, Z, acc, stats, ab, h16, stream);

  // layer 1: h16 bf16 [N,128] -> d_out f32 [N,128]
  run_layer<128, true, false>(h16, Wt1, b1, fcW1, fcb1, g1, be1, off, srt,
                              sOut, sIn, Y, Z, acc, stats, ab, d_out, stream);
}

// Round 6
// 1770.934 us; speedup vs baseline: 1.0442x; 1.0442x over previous
//
#include <hip/hip_runtime.h>
#include <hip/hip_bf16.h>
#include <math.h>

#define NN 100000
#define HID 128
#define EPSV 1e-5f

typedef short bf16x8 __attribute__((ext_vector_type(8)));
typedef float f32x4 __attribute__((ext_vector_type(4)));
typedef unsigned short u16;

__device__ __forceinline__ u16 f2b(float f) {       // f32 -> bf16 RNE (bit-twiddle)
  unsigned u = __builtin_bit_cast(unsigned, f);
  u += 0x7FFFu + ((u >> 16) & 1u);
  return (u16)(u >> 16);
}
__device__ __forceinline__ float b2f(u16 h) {
  unsigned u = ((unsigned)h) << 16;
  return __builtin_bit_cast(float, u);
}

#define AS1(p) ((__attribute__((address_space(1))) void*)(p))
#define AS3(p) ((__attribute__((address_space(3))) void*)(p))

// ---------------- utility kernels ----------------

static __global__ void k_zero(float* __restrict__ p, int n) {
  int i = blockIdx.x * blockDim.x + threadIdx.x;
  if (i < n) p[i] = 0.f;
}

static __global__ void k_zero_i(int* __restrict__ p, int n) {
  int i = blockIdx.x * blockDim.x + threadIdx.x;
  if (i < n) p[i] = 0;
}

static __global__ void k_deg(const int* __restrict__ src, const int* __restrict__ dst,
                             int E, float* __restrict__ outdeg, float* __restrict__ indeg) {
  int e = blockIdx.x * blockDim.x + threadIdx.x;
  if (e < E) {
    atomicAdd(&outdeg[src[e]], 1.f);
    atomicAdd(&indeg[dst[e]], 1.f);
  }
}

static __global__ void k_counts(const float* __restrict__ indegRaw, int* __restrict__ counts, int n3) {
  int i = blockIdx.x * blockDim.x + threadIdx.x;
  if (i < n3) counts[i] = (int)indegRaw[i];
  else if (i == n3) counts[i] = 0;
}

static __global__ void k_rsqrt_clip(float* __restrict__ p, int n) {
  int i = blockIdx.x * blockDim.x + threadIdx.x;
  if (i < n) p[i] = rsqrtf(fmaxf(p[i], 1.f));
}

// ---------------- exclusive scan (two-level) ----------------
static __global__ void k_scan1(const int* __restrict__ in, int* __restrict__ out,
                               int* __restrict__ aux, int n) {
  __shared__ int s[256];
  int t = threadIdx.x, i = blockIdx.x * 256 + t;
  int v = (i < n) ? in[i] : 0;
  s[t] = v; __syncthreads();
#pragma unroll
  for (int d = 1; d < 256; d <<= 1) {
    int x = (t >= d) ? s[t - d] : 0;
    __syncthreads();
    s[t] += x;
    __syncthreads();
  }
  if (i < n) out[i] = s[t] - v;
  if (t == 255) aux[blockIdx.x] = s[255];
}

static __global__ void k_scan2(int* __restrict__ aux, int nb) {
  __shared__ int s[256];
  __shared__ int carry;
  int t = threadIdx.x;
  if (t == 0) carry = 0;
  __syncthreads();
  for (int base = 0; base < nb; base += 256) {
    int i = base + t;
    int v = (i < nb) ? aux[i] : 0;
    s[t] = v; __syncthreads();
#pragma unroll
    for (int d = 1; d < 256; d <<= 1) {
      int x = (t >= d) ? s[t - d] : 0;
      __syncthreads();
      s[t] += x;
      __syncthreads();
    }
    int excl = s[t] - v + carry;
    if (i < nb) aux[i] = excl;
    int tot = s[255];
    __syncthreads();
    if (t == 0) carry += tot;
    __syncthreads();
  }
}

static __global__ void k_scan3(int* __restrict__ out, const int* __restrict__ aux, int n) {
  int i = blockIdx.x * 256 + threadIdx.x;
  if (i < n) out[i] += aux[blockIdx.x];
}

static __global__ void k_fill(const int* __restrict__ src, const int* __restrict__ dst, int E,
                              const int* __restrict__ off, int* __restrict__ cur,
                              int rbase, int* __restrict__ srt) {
  int e = blockIdx.x * blockDim.x + threadIdx.x;
  if (e < E) {
    int d = dst[e];
    int p = off[rbase + d] + atomicAdd(&cur[rbase + d], 1);
    srt[p] = src[e];
  }
}

// W [3][K][128] f32 -> Wt [3*128][K] bf16 (row = rel*128 + outcol)
static __global__ void k_cvt_w(const float* __restrict__ W, u16* __restrict__ Wt, int K) {
  int i = blockIdx.x * blockDim.x + threadIdx.x;
  int tot = 3 * K * 128;
  if (i < tot) {
    int rel = i / (K * 128);
    int rem = i - rel * K * 128;
    int k = rem >> 7;
    int c = rem & 127;
    Wt[((size_t)rel * 128 + c) * K + k] = f2b(W[i]);
  }
}

// ---------------- pipelined fused MFMA GEMM ----------------
// Y[row, c] = sout[c>>7][row] * (A[row,:] @ Wt[c,:]);  BM=128 x BN=384, BK=32.
// 8 waves (2m x 4n), wave tile 64x96 (4x6 frags of 16x16x32).
// 3 LDS buffers, 2-deep global_load_lds prefetch, counted vmcnt (never drains in loop),
// ONE raw s_barrier per K-step.  A staged as raw f32 (AF32) and converted after ds_read,
// or staged as bf16 directly (layer 1).
template<int K, bool AF32>
__global__ __launch_bounds__(512)
void k_gemm_pipe(const void* __restrict__ Av,
                 const u16* __restrict__ Wt,    // [384][K] bf16
                 const float* __restrict__ sout,// [3][NN]
                 u16* __restrict__ Y,           // [M][384] bf16
                 int M)
{
  constexpr int A_BYTES = AF32 ? (128 * 32 * 4) : (128 * 32 * 2);  // 16 KB / 8 KB
  constexpr int B_BYTES = 384 * 32 * 2;                            // 24 KB
  constexpr int BUF_U16 = (A_BYTES + B_BYTES) / 2;
  __shared__ u16 lds[3][BUF_U16];   // 120 KB (AF32) / 96 KB

  const int row0 = blockIdx.x * 128;
  const int t    = threadIdx.x;
  const int lane = t & 63;
  const int w    = t >> 6;          // 0..7
  const int wm   = w >> 2;          // 0..1
  const int wn   = w & 3;           // 0..3
  const int l15  = lane & 15, l4 = lane >> 4;
  const int kl   = l4 * 8;
  const int nk   = K / 32;

  int ar = row0 + w * 16 + l15;  if (ar >= M) ar = M - 1;   // clamped dup read

  const float* Af = (const float*)Av;
  const u16*   Ab = (const u16*)Av;

  // per-wave B staging rows: w*48 + {0,16,32} + l15
  const u16* gb0 = Wt + (size_t)(w * 48 +      l15) * K + kl;
  const u16* gb1 = Wt + (size_t)(w * 48 + 16 + l15) * K + kl;
  const u16* gb2 = Wt + (size_t)(w * 48 + 32 + l15) * K + kl;

  // NOTE: global_load_lds LDS dest is wave-uniform base (+ lane*16 by HW); global src is per-lane.
  auto STAGE = [&](int buf, int k0) {
    u16* L = &lds[buf][0];
    if constexpr (AF32) {
      const float* sa = Af + (size_t)ar * K + k0 + l4 * 8;
      __builtin_amdgcn_global_load_lds(AS1(sa),     AS3(L + (w * 2048) / 2),          16, 0, 0);
      __builtin_amdgcn_global_load_lds(AS1(sa + 4), AS3(L + (w * 2048 + 1024) / 2),   16, 0, 0);
    } else {
      const u16* sa = Ab + (size_t)ar * K + k0 + kl;
      __builtin_amdgcn_global_load_lds(AS1(sa),     AS3(L + (w * 1024) / 2),          16, 0, 0);
    }
    u16* Bd = L + A_BYTES / 2;
    __builtin_amdgcn_global_load_lds(AS1(gb0 + k0), AS3(Bd + (w * 3 + 0) * 512), 16, 0, 0);
    __builtin_amdgcn_global_load_lds(AS1(gb1 + k0), AS3(Bd + (w * 3 + 1) * 512), 16, 0, 0);
    __builtin_amdgcn_global_load_lds(AS1(gb2 + k0), AS3(Bd + (w * 3 + 2) * 512), 16, 0, 0);
  };

  f32x4 acc[4][6];
#pragma unroll
  for (int m = 0; m < 4; ++m)
#pragma unroll
    for (int n = 0; n < 6; ++n) acc[m][n] = (f32x4){0.f, 0.f, 0.f, 0.f};

  // prologue: 2-deep prefetch
  STAGE(0, 0);
  if (nk > 1) STAGE(1, 32);

  for (int k = 0; k < nk; ++k) {
    // wait until buffer k has landed; keep the newest stage in flight (counted vmcnt)
    if (k + 1 < nk) {
      if constexpr (AF32) asm volatile("s_waitcnt vmcnt(5)" ::: "memory");
      else                asm volatile("s_waitcnt vmcnt(4)" ::: "memory");
    } else {
      asm volatile("s_waitcnt vmcnt(0)" ::: "memory");
    }
    __builtin_amdgcn_sched_barrier(0);
    __builtin_amdgcn_s_barrier();
    __builtin_amdgcn_sched_barrier(0);

    if (k + 2 < nk) STAGE((k + 2) % 3, (k + 2) * 32);

    const int cur = k % 3;
    bf16x8 a[4], b[6];
    if constexpr (AF32) {
      const float* Al = (const float*)&lds[cur][0];
#pragma unroll
      for (int m = 0; m < 4; ++m) {
        f32x4 lo = *(const f32x4*)&Al[(wm * 4 + m) * 512 + lane * 4];
        f32x4 hi = *(const f32x4*)&Al[(wm * 4 + m) * 512 + 256 + lane * 4];
        union { bf16x8 v; u16 u[8]; } q;
#pragma unroll
        for (int j = 0; j < 4; ++j) {
          q.u[j]     = __builtin_bit_cast(u16, __float2bfloat16(lo[j]));
          q.u[4 + j] = __builtin_bit_cast(u16, __float2bfloat16(hi[j]));
        }
        a[m] = q.v;
      }
    } else {
      const u16* Al = &lds[cur][0];
#pragma unroll
      for (int m = 0; m < 4; ++m) a[m] = *(const bf16x8*)&Al[(wm * 4 + m) * 512 + lane * 8];
    }
    {
      const u16* Bl = &lds[cur][A_BYTES / 2];
#pragma unroll
      for (int n = 0; n < 6; ++n) b[n] = *(const bf16x8*)&Bl[(wn * 6 + n) * 512 + lane * 8];
    }

#pragma unroll
    for (int m = 0; m < 4; ++m)
#pragma unroll
      for (int n = 0; n < 6; ++n)
        acc[m][n] = __builtin_amdgcn_mfma_f32_16x16x32_bf16(a[m], b[n], acc[m][n], 0, 0, 0);
  }

  // epilogue: C layout col=lane&15, row=(lane>>4)*4+reg
#pragma unroll
  for (int m = 0; m < 4; ++m) {
    const int rb = row0 + wm * 64 + m * 16 + l4 * 4;
#pragma unroll
    for (int j = 0; j < 4; ++j) {
      const int row = rb + j;
      if (row < M) {
        u16* yrow = Y + (size_t)row * 384;
#pragma unroll
        for (int n = 0; n < 6; ++n) {
          const int c = wn * 96 + n * 16;
          const float sc = sout[(size_t)(c >> 7) * NN + row];
          yrow[c + l15] = f2b(acc[m][n][j] * sc);
        }
      }
    }
  }
}

// ---------------- CSR gather ----------------
static __global__ __launch_bounds__(256)
void k_gather(const int* __restrict__ off, const int* __restrict__ srt,
              const float* __restrict__ sin_, const u16* __restrict__ Y,
              const float* __restrict__ b, float* __restrict__ acc)
{
  int d = blockIdx.x * 4 + (threadIdx.x >> 6);
  if (d >= NN) return;
  int c = (threadIdx.x & 63) * 2;
  float v0 = b[c]     + b[128 + c]     + b[256 + c];
  float v1 = b[c + 1] + b[128 + c + 1] + b[256 + c + 1];
#pragma unroll
  for (int r = 0; r < 3; ++r) {
    int base = r * NN + d;
    int j0 = off[base], j1 = off[base + 1];
    float p0 = 0.f, p1 = 0.f;
    for (int j = j0; j < j1; ++j) {
      int s = srt[j];
      unsigned u = *(const unsigned*)&Y[(size_t)s * 384 + r * 128 + c];
      p0 += b2f((u16)(u & 0xFFFFu));
      p1 += b2f((u16)(u >> 16));
    }
    float sc = sin_[base];
    v0 += p0 * sc;
    v1 += p1 * sc;
  }
  *(float2*)&acc[(size_t)d * 128 + c] = make_float2(v0, v1);
}

// ---------------- FC (128x128) + bias + ReLU ----------------
static __global__ __launch_bounds__(256)
void k_fc_relu(const float* __restrict__ X, int M,
               const float* __restrict__ Wfc, const float* __restrict__ bfc,
               float* __restrict__ Z)
{
  __shared__ float Ws[128 * 64];
  __shared__ float xs[4][128];
  const int j0 = blockIdx.y * 64;
  const int t = threadIdx.x;

  for (int i = t; i < 128 * 64; i += 256) {
    int k = i >> 6, c = i & 63;
    Ws[i] = Wfc[k * 128 + j0 + c];
  }
  const int rl = t >> 6;
  const int c  = t & 63;
  const float bb = bfc[j0 + c];
  __syncthreads();

  for (int row0 = blockIdx.x * 4; row0 < M; row0 += gridDim.x * 4) {
    int row = row0 + rl;
    if (row < M) {
      xs[rl][c]      = X[(size_t)row * 128 + c];
      xs[rl][c + 64] = X[(size_t)row * 128 + c + 64];
    }
    __syncthreads();
    if (row < M) {
      float acc = bb;
#pragma unroll
      for (int k = 0; k < 128; ++k)
        acc = fmaf(xs[rl][k], Ws[k * 64 + c], acc);
      Z[(size_t)row * 128 + j0 + c] = fmaxf(acc, 0.f);
    }
    __syncthreads();
  }
}

// ---------------- BatchNorm ----------------
static __global__ void k_bn_stats(const float* __restrict__ Z, int M, float* __restrict__ stats) {
  int col = threadIdx.x;  // 128
  float s = 0.f, s2 = 0.f;
  for (int row = blockIdx.x; row < M; row += gridDim.x) {
    float v = Z[(size_t)row * 128 + col];
    s += v;
    s2 += v * v;
  }
  atomicAdd(&stats[col], s);
  atomicAdd(&stats[128 + col], s2);
}

static __global__ void k_bn_finalize(const float* __restrict__ stats, int M,
                                     const float* __restrict__ g, const float* __restrict__ beta,
                                     float* __restrict__ ab) {
  int j = threadIdx.x;  // 128
  float m  = stats[j] / (float)M;
  float v  = stats[128 + j] / (float)M - m * m;
  float inv = rsqrtf(v + EPSV) * g[j];
  ab[j]       = inv;
  ab[128 + j] = beta[j] - m * inv;
}

template<bool OUT_BF16>
static __global__ void k_bn_apply(const float* __restrict__ Z, const float* __restrict__ ab,
                                  void* __restrict__ out, int n) {
  int i = blockIdx.x * blockDim.x + threadIdx.x;
  if (i < n) {
    int j = i & 127;
    float v = Z[i] * ab[j] + ab[128 + j];
    if constexpr (OUT_BF16) ((u16*)out)[i] = f2b(v);
    else                    ((float*)out)[i] = v;
  }
}

// ---------------- host-side layer driver ----------------

template<int K, bool AF32, bool OUT_BF16>
static void run_layer(const void* X,
                      const u16* Wt, const float* b,
                      const float* fcW, const float* fcb,
                      const float* g, const float* beta,
                      const int* off, const int* srt,
                      float* sOut, float* sIn, u16* Y, float* Z, float* acc,
                      float* stats, float* ab, void* out, hipStream_t stream)
{
  const int NT = (NN + 127) / 128;
  k_gemm_pipe<K, AF32><<<NT, 512, 0, stream>>>(X, Wt, sOut, Y, NN);

  k_gather<<<(NN + 3) / 4, 256, 0, stream>>>(off, srt, sIn, Y, b, acc);

  k_fc_relu<<<dim3(2048, 2), 256, 0, stream>>>(acc, NN, fcW, fcb, Z);

  k_zero<<<1, 256, 0, stream>>>(stats, 256);
  k_bn_stats<<<1024, 128, 0, stream>>>(Z, NN, stats);
  k_bn_finalize<<<1, 128, 0, stream>>>(stats, NN, g, beta, ab);
  k_bn_apply<OUT_BF16><<<(NN * HID + 255) / 256, 256, 0, stream>>>(Z, ab, out, NN * HID);
}

extern "C" void kernel_launch(void* const* d_in, const int* in_sizes, int n_in,
                              void* d_out, int out_size, void* d_ws, size_t ws_size,
                              hipStream_t stream)
{
  const float* x    = (const float*)d_in[0];
  const int*   seq  = (const int*)d_in[1];
  const int*   knn  = (const int*)d_in[2];
  const int*   dis  = (const int*)d_in[3];
  const float* W0   = (const float*)d_in[4];
  const float* b0   = (const float*)d_in[5];
  const float* fcW0 = (const float*)d_in[6];
  const float* fcb0 = (const float*)d_in[7];
  const float* g0   = (const float*)d_in[8];
  const float* be0  = (const float*)d_in[9];
  const float* W1   = (const float*)d_in[10];
  const float* b1   = (const float*)d_in[11];
  const float* fcW1 = (const float*)d_in[12];
  const float* fcb1 = (const float*)d_in[13];
  const float* g1   = (const float*)d_in[14];
  const float* be1  = (const float*)d_in[15];

  const int E[3] = { in_sizes[1] / 2, in_sizes[2] / 2, in_sizes[3] / 2 };
  const int* srcs[3] = { seq, knn, dis };

  const size_t N = NN;
  const int M3 = 3 * NN;

  float* ws    = (float*)d_ws;
  float* sOut  = ws;                        // 3N
  float* sIn   = sOut + 3 * N;              // 3N
  float* acc   = sIn + 3 * N;               // N*128
  float* stats = acc + N * 128;             // 256
  float* ab    = stats + 256;               // 256
  u16*   Y     = (u16*)(ab + 256);          // N*384 bf16 (Z aliases: Y dead after gather)
  float* Z     = (float*)Y;                 // N*128 f32
  u16*   h16   = Y + N * 384;               // N*128 bf16
  u16*   Wt0   = h16 + N * 128;             // 3*128*1280
  u16*   Wt1   = Wt0 + 3 * 128 * 1280;      // 3*128*128
  int*   counts= (int*)(Wt1 + 3 * 128 * 128);
  int*   off   = counts + (M3 + 1);
  int*   aux   = off + (M3 + 1);
  int*   cur   = aux + 1536;
  int*   srt   = cur + M3;                  // ETOT ints

  // weight transpose+convert
  k_cvt_w<<<(3 * 1280 * 128 + 255) / 256, 256, 0, stream>>>(W0, Wt0, 1280);
  k_cvt_w<<<(3 * 128 * 128 + 255) / 256, 256, 0, stream>>>(W1, Wt1, 128);

  // degrees
  k_zero<<<(6 * NN + 255) / 256, 256, 0, stream>>>(sOut, 6 * NN);
  for (int r = 0; r < 3; ++r) {
    k_deg<<<(E[r] + 255) / 256, 256, 0, stream>>>(
        srcs[r], srcs[r] + E[r], E[r], sOut + (size_t)r * N, sIn + (size_t)r * N);
  }
  k_counts<<<(M3 + 1 + 255) / 256, 256, 0, stream>>>(sIn, counts, M3);
  k_rsqrt_clip<<<(6 * NN + 255) / 256, 256, 0, stream>>>(sOut, 6 * NN);

  // CSR: exclusive scan of counts[M3+1] -> off
  const int nsc = M3 + 1;
  const int nb  = (nsc + 255) / 256;
  k_scan1<<<nb, 256, 0, stream>>>(counts, off, aux, nsc);
  k_scan2<<<1, 256, 0, stream>>>(aux, nb);
  k_scan3<<<nb, 256, 0, stream>>>(off, aux, nsc);

  k_zero_i<<<(M3 + 255) / 256, 256, 0, stream>>>(cur, M3);
  for (int r = 0; r < 3; ++r) {
    k_fill<<<(E[r] + 255) / 256, 256, 0, stream>>>(
        srcs[r], srcs[r] + E[r], E[r], off, cur, r * NN, srt);
  }

  // layer 0: x f32 [N,1280] -> h16 bf16 [N,128]
  run_layer<1280, true, true>(x, Wt0, b0, fcW0, fcb0, g0, be0, off, srt,
                              sOut, sIn, Y, Z, acc, stats, ab, h16, stream);

  // layer 1: h16 bf16 [N,128] -> d_out f32 [N,128]
  run_layer<128, false, false>(h16, Wt1, b1, fcW1, fcb1, g1, be1, off, srt,
                               sOut, sIn, Y, Z, acc, stats, ab, d_out, stream);
}

// Round 7
// 1298.532 us; speedup vs baseline: 1.4241x; 1.3638x over previous
//
#include <hip/hip_runtime.h>
#include <hip/hip_bf16.h>
#include <math.h>

#define NN 100000
#define HID 128
#define EPSV 1e-5f

typedef short bf16x8 __attribute__((ext_vector_type(8)));
typedef float f32x4 __attribute__((ext_vector_type(4)));
typedef unsigned short u16;

__device__ __forceinline__ u16 f2b(float f) {       // f32 -> bf16 RNE (bit-twiddle)
  unsigned u = __builtin_bit_cast(unsigned, f);
  u += 0x7FFFu + ((u >> 16) & 1u);
  return (u16)(u >> 16);
}
__device__ __forceinline__ float b2f(u16 h) {
  unsigned u = ((unsigned)h) << 16;
  return __builtin_bit_cast(float, u);
}

#define AS1(p) ((__attribute__((address_space(1))) void*)(p))
#define AS3(p) ((__attribute__((address_space(3))) void*)(p))

// ---------------- utility kernels ----------------

static __global__ void k_zero(float* __restrict__ p, int n) {
  int i = blockIdx.x * blockDim.x + threadIdx.x;
  if (i < n) p[i] = 0.f;
}

static __global__ void k_zero_i(int* __restrict__ p, int n) {
  int i = blockIdx.x * blockDim.x + threadIdx.x;
  if (i < n) p[i] = 0;
}

static __global__ void k_deg(const int* __restrict__ src, const int* __restrict__ dst,
                             int E, float* __restrict__ outdeg, float* __restrict__ indeg) {
  int e = blockIdx.x * blockDim.x + threadIdx.x;
  if (e < E) {
    atomicAdd(&outdeg[src[e]], 1.f);
    atomicAdd(&indeg[dst[e]], 1.f);
  }
}

static __global__ void k_counts(const float* __restrict__ indegRaw, int* __restrict__ counts, int n3) {
  int i = blockIdx.x * blockDim.x + threadIdx.x;
  if (i < n3) counts[i] = (int)indegRaw[i];
  else if (i == n3) counts[i] = 0;
}

static __global__ void k_rsqrt_clip(float* __restrict__ p, int n) {
  int i = blockIdx.x * blockDim.x + threadIdx.x;
  if (i < n) p[i] = rsqrtf(fmaxf(p[i], 1.f));
}

// ---------------- exclusive scan (two-level) ----------------
static __global__ void k_scan1(const int* __restrict__ in, int* __restrict__ out,
                               int* __restrict__ aux, int n) {
  __shared__ int s[256];
  int t = threadIdx.x, i = blockIdx.x * 256 + t;
  int v = (i < n) ? in[i] : 0;
  s[t] = v; __syncthreads();
#pragma unroll
  for (int d = 1; d < 256; d <<= 1) {
    int x = (t >= d) ? s[t - d] : 0;
    __syncthreads();
    s[t] += x;
    __syncthreads();
  }
  if (i < n) out[i] = s[t] - v;
  if (t == 255) aux[blockIdx.x] = s[255];
}

static __global__ void k_scan2(int* __restrict__ aux, int nb) {
  __shared__ int s[256];
  __shared__ int carry;
  int t = threadIdx.x;
  if (t == 0) carry = 0;
  __syncthreads();
  for (int base = 0; base < nb; base += 256) {
    int i = base + t;
    int v = (i < nb) ? aux[i] : 0;
    s[t] = v; __syncthreads();
#pragma unroll
    for (int d = 1; d < 256; d <<= 1) {
      int x = (t >= d) ? s[t - d] : 0;
      __syncthreads();
      s[t] += x;
      __syncthreads();
    }
    int excl = s[t] - v + carry;
    if (i < nb) aux[i] = excl;
    int tot = s[255];
    __syncthreads();
    if (t == 0) carry += tot;
    __syncthreads();
  }
}

static __global__ void k_scan3(int* __restrict__ out, const int* __restrict__ aux, int n) {
  int i = blockIdx.x * 256 + threadIdx.x;
  if (i < n) out[i] += aux[blockIdx.x];
}

static __global__ void k_fill(const int* __restrict__ src, const int* __restrict__ dst, int E,
                              const int* __restrict__ off, int* __restrict__ cur,
                              int rbase, int* __restrict__ srt) {
  int e = blockIdx.x * blockDim.x + threadIdx.x;
  if (e < E) {
    int d = dst[e];
    int p = off[rbase + d] + atomicAdd(&cur[rbase + d], 1);
    srt[p] = src[e];
  }
}

// W [3][K][128] f32 -> Wt [3*128][K] bf16 (row = rel*128 + outcol)
static __global__ void k_cvt_w(const float* __restrict__ W, u16* __restrict__ Wt, int K) {
  int i = blockIdx.x * blockDim.x + threadIdx.x;
  int tot = 3 * K * 128;
  if (i < tot) {
    int rel = i / (K * 128);
    int rem = i - rel * K * 128;
    int k = rem >> 7;
    int c = rem & 127;
    Wt[((size_t)rel * 128 + c) * K + k] = f2b(W[i]);
  }
}

// fcW [128][128] f32 -> Bt [c][k] bf16 (transposed)
static __global__ void k_cvt_fcw(const float* __restrict__ W, u16* __restrict__ Bt) {
  int i = blockIdx.x * blockDim.x + threadIdx.x;   // 16384
  if (i < 128 * 128) {
    int k = i >> 7, c = i & 127;
    Bt[c * 128 + k] = f2b(W[i]);
  }
}

// ---------------- pipelined fused MFMA GEMM ----------------
// Y[row, c] = sout[c>>7][row] * (A[row,:] @ Wt[c,:]);  BM=128 x BN=384, BK=32.
// 8 waves (2m x 4n), wave tile 64x96 (4x6 frags of 16x16x32).
// 3 LDS buffers, 2-deep global_load_lds prefetch, counted vmcnt, ONE s_barrier per K-step.
template<int K, bool AF32>
__global__ __launch_bounds__(512)
void k_gemm_pipe(const void* __restrict__ Av,
                 const u16* __restrict__ Wt,    // [384][K] bf16
                 const float* __restrict__ sout,// [3][NN]
                 u16* __restrict__ Y,           // [M][384] bf16
                 int M)
{
  constexpr int A_BYTES = AF32 ? (128 * 32 * 4) : (128 * 32 * 2);  // 16 KB / 8 KB
  constexpr int B_BYTES = 384 * 32 * 2;                            // 24 KB
  constexpr int BUF_U16 = (A_BYTES + B_BYTES) / 2;
  __shared__ u16 lds[3][BUF_U16];   // 120 KB (AF32) / 96 KB

  const int row0 = blockIdx.x * 128;
  const int t    = threadIdx.x;
  const int lane = t & 63;
  const int w    = t >> 6;          // 0..7
  const int wm   = w >> 2;          // 0..1
  const int wn   = w & 3;           // 0..3
  const int l15  = lane & 15, l4 = lane >> 4;
  const int kl   = l4 * 8;
  const int nk   = K / 32;

  int ar = row0 + w * 16 + l15;  if (ar >= M) ar = M - 1;   // clamped dup read

  const float* Af = (const float*)Av;
  const u16*   Ab = (const u16*)Av;

  const u16* gb0 = Wt + (size_t)(w * 48 +      l15) * K + kl;
  const u16* gb1 = Wt + (size_t)(w * 48 + 16 + l15) * K + kl;
  const u16* gb2 = Wt + (size_t)(w * 48 + 32 + l15) * K + kl;

  auto STAGE = [&](int buf, int k0) {
    u16* L = &lds[buf][0];
    if constexpr (AF32) {
      const float* sa = Af + (size_t)ar * K + k0 + l4 * 8;
      __builtin_amdgcn_global_load_lds(AS1(sa),     AS3(L + (w * 2048) / 2),          16, 0, 0);
      __builtin_amdgcn_global_load_lds(AS1(sa + 4), AS3(L + (w * 2048 + 1024) / 2),   16, 0, 0);
    } else {
      const u16* sa = Ab + (size_t)ar * K + k0 + kl;
      __builtin_amdgcn_global_load_lds(AS1(sa),     AS3(L + (w * 1024) / 2),          16, 0, 0);
    }
    u16* Bd = L + A_BYTES / 2;
    __builtin_amdgcn_global_load_lds(AS1(gb0 + k0), AS3(Bd + (w * 3 + 0) * 512), 16, 0, 0);
    __builtin_amdgcn_global_load_lds(AS1(gb1 + k0), AS3(Bd + (w * 3 + 1) * 512), 16, 0, 0);
    __builtin_amdgcn_global_load_lds(AS1(gb2 + k0), AS3(Bd + (w * 3 + 2) * 512), 16, 0, 0);
  };

  f32x4 acc[4][6];
#pragma unroll
  for (int m = 0; m < 4; ++m)
#pragma unroll
    for (int n = 0; n < 6; ++n) acc[m][n] = (f32x4){0.f, 0.f, 0.f, 0.f};

  STAGE(0, 0);
  if (nk > 1) STAGE(1, 32);

  for (int k = 0; k < nk; ++k) {
    if (k + 1 < nk) {
      if constexpr (AF32) asm volatile("s_waitcnt vmcnt(5)" ::: "memory");
      else                asm volatile("s_waitcnt vmcnt(4)" ::: "memory");
    } else {
      asm volatile("s_waitcnt vmcnt(0)" ::: "memory");
    }
    __builtin_amdgcn_sched_barrier(0);
    __builtin_amdgcn_s_barrier();
    __builtin_amdgcn_sched_barrier(0);

    if (k + 2 < nk) STAGE((k + 2) % 3, (k + 2) * 32);

    const int cur = k % 3;
    bf16x8 a[4], b[6];
    if constexpr (AF32) {
      const float* Al = (const float*)&lds[cur][0];
#pragma unroll
      for (int m = 0; m < 4; ++m) {
        f32x4 lo = *(const f32x4*)&Al[(wm * 4 + m) * 512 + lane * 4];
        f32x4 hi = *(const f32x4*)&Al[(wm * 4 + m) * 512 + 256 + lane * 4];
        union { bf16x8 v; u16 u[8]; } q;
#pragma unroll
        for (int j = 0; j < 4; ++j) {
          q.u[j]     = __builtin_bit_cast(u16, __float2bfloat16(lo[j]));
          q.u[4 + j] = __builtin_bit_cast(u16, __float2bfloat16(hi[j]));
        }
        a[m] = q.v;
      }
    } else {
      const u16* Al = &lds[cur][0];
#pragma unroll
      for (int m = 0; m < 4; ++m) a[m] = *(const bf16x8*)&Al[(wm * 4 + m) * 512 + lane * 8];
    }
    {
      const u16* Bl = &lds[cur][A_BYTES / 2];
#pragma unroll
      for (int n = 0; n < 6; ++n) b[n] = *(const bf16x8*)&Bl[(wn * 6 + n) * 512 + lane * 8];
    }

    __builtin_amdgcn_s_setprio(1);
#pragma unroll
    for (int m = 0; m < 4; ++m)
#pragma unroll
      for (int n = 0; n < 6; ++n)
        acc[m][n] = __builtin_amdgcn_mfma_f32_16x16x32_bf16(a[m], b[n], acc[m][n], 0, 0, 0);
    __builtin_amdgcn_s_setprio(0);
  }

  // epilogue: C layout col=lane&15, row=(lane>>4)*4+reg
#pragma unroll
  for (int m = 0; m < 4; ++m) {
    const int rb = row0 + wm * 64 + m * 16 + l4 * 4;
#pragma unroll
    for (int j = 0; j < 4; ++j) {
      const int row = rb + j;
      if (row < M) {
        u16* yrow = Y + (size_t)row * 384;
#pragma unroll
        for (int n = 0; n < 6; ++n) {
          const int c = wn * 96 + n * 16;
          const float sc = sout[(size_t)(c >> 7) * NN + row];
          yrow[c + l15] = f2b(acc[m][n][j] * sc);
        }
      }
    }
  }
}

// ---------------- CSR gather (4x unrolled for ILP on the L3 latency chain) ----------------
// writes acc as PACKED bf16 (u32 of 2 cols) for the MFMA FC that follows.
static __global__ __launch_bounds__(256)
void k_gather(const int* __restrict__ off, const int* __restrict__ srt,
              const float* __restrict__ sin_, const u16* __restrict__ Y,
              const float* __restrict__ b, u16* __restrict__ acc16)
{
  int d = blockIdx.x * 4 + (threadIdx.x >> 6);
  if (d >= NN) return;
  int c = (threadIdx.x & 63) * 2;
  float v0 = b[c]     + b[128 + c]     + b[256 + c];
  float v1 = b[c + 1] + b[128 + c + 1] + b[256 + c + 1];
#pragma unroll
  for (int r = 0; r < 3; ++r) {
    int base = r * NN + d;
    int j0 = off[base], j1 = off[base + 1];
    float p0 = 0.f, p1 = 0.f;
    int j = j0;
    for (; j + 4 <= j1; j += 4) {
      int s0 = srt[j], s1 = srt[j + 1], s2 = srt[j + 2], s3 = srt[j + 3];
      unsigned u0 = *(const unsigned*)&Y[(size_t)s0 * 384 + r * 128 + c];
      unsigned u1 = *(const unsigned*)&Y[(size_t)s1 * 384 + r * 128 + c];
      unsigned u2 = *(const unsigned*)&Y[(size_t)s2 * 384 + r * 128 + c];
      unsigned u3 = *(const unsigned*)&Y[(size_t)s3 * 384 + r * 128 + c];
      p0 += b2f((u16)(u0 & 0xFFFFu)) + b2f((u16)(u1 & 0xFFFFu))
          + b2f((u16)(u2 & 0xFFFFu)) + b2f((u16)(u3 & 0xFFFFu));
      p1 += b2f((u16)(u0 >> 16)) + b2f((u16)(u1 >> 16))
          + b2f((u16)(u2 >> 16)) + b2f((u16)(u3 >> 16));
    }
    for (; j < j1; ++j) {
      int s = srt[j];
      unsigned u = *(const unsigned*)&Y[(size_t)s * 384 + r * 128 + c];
      p0 += b2f((u16)(u & 0xFFFFu));
      p1 += b2f((u16)(u >> 16));
    }
    float sc = sin_[base];
    v0 += p0 * sc;
    v1 += p1 * sc;
  }
  unsigned out = (unsigned)f2b(v0) | ((unsigned)f2b(v1) << 16);
  *(unsigned*)&acc16[(size_t)d * 128 + c] = out;
}

// ---------------- FC (128x128) via MFMA: Z = relu(acc16 @ fcW + bias), f32 out ----------------
// 8 waves (2m x 4n), wave tile 64x32 (4x2 frags). B (fcWt, 32 KB, L2-resident) fully in regs;
// all 4 A K-steps pre-staged via global_load_lds -> ONE vmcnt(0) + ONE barrier per block.
static __global__ __launch_bounds__(512)
void k_fc_mfma(const u16* __restrict__ A,      // [M][128] bf16
               const u16* __restrict__ Bt,     // [128][128] bf16 (row=outcol)
               const float* __restrict__ bias,
               float* __restrict__ Z, int M)
{
  __shared__ u16 Ab[4][4096];   // 32 KB: 4 ksteps x (128 rows x 32 k) frag-major

  const int row0 = blockIdx.x * 128;
  const int t    = threadIdx.x;
  const int lane = t & 63;
  const int w    = t >> 6;
  const int wm   = w >> 2;          // 0..1
  const int wn   = w & 3;           // 0..3
  const int l15  = lane & 15, l4 = lane >> 4;
  const int kl   = l4 * 8;

  int ar = row0 + w * 16 + l15;  if (ar >= M) ar = M - 1;

  // B fragments straight to registers (each block reads the same 32 KB -> L2 hits)
  bf16x8 br[2][4];
#pragma unroll
  for (int n = 0; n < 2; ++n)
#pragma unroll
    for (int ks = 0; ks < 4; ++ks)
      br[n][ks] = *(const bf16x8*)&Bt[(size_t)(wn * 32 + n * 16 + l15) * 128 + ks * 32 + kl];

  // stage ALL of A (4 ksteps, 1 gload_lds per wave per step)
#pragma unroll
  for (int ks = 0; ks < 4; ++ks)
    __builtin_amdgcn_global_load_lds(AS1(A + (size_t)ar * 128 + ks * 32 + kl),
                                     AS3(&Ab[ks][w * 512]), 16, 0, 0);

  asm volatile("s_waitcnt vmcnt(0)" ::: "memory");
  __syncthreads();

  f32x4 acc[4][2];
#pragma unroll
  for (int m = 0; m < 4; ++m) { acc[m][0] = (f32x4){0,0,0,0}; acc[m][1] = (f32x4){0,0,0,0}; }

#pragma unroll
  for (int ks = 0; ks < 4; ++ks) {
#pragma unroll
    for (int m = 0; m < 4; ++m) {
      bf16x8 a = *(const bf16x8*)&Ab[ks][(wm * 4 + m) * 512 + lane * 8];
      acc[m][0] = __builtin_amdgcn_mfma_f32_16x16x32_bf16(a, br[0][ks], acc[m][0], 0, 0, 0);
      acc[m][1] = __builtin_amdgcn_mfma_f32_16x16x32_bf16(a, br[1][ks], acc[m][1], 0, 0, 0);
    }
  }

#pragma unroll
  for (int m = 0; m < 4; ++m) {
    const int rb = row0 + wm * 64 + m * 16 + l4 * 4;
#pragma unroll
    for (int j = 0; j < 4; ++j) {
      const int row = rb + j;
      if (row < M) {
#pragma unroll
        for (int n = 0; n < 2; ++n) {
          const int cc = wn * 32 + n * 16 + l15;
          Z[(size_t)row * 128 + cc] = fmaxf(acc[m][n][j] + bias[cc], 0.f);
        }
      }
    }
  }
}

// ---------------- BatchNorm ----------------
static __global__ void k_bn_stats(const float* __restrict__ Z, int M, float* __restrict__ stats) {
  int col = threadIdx.x;  // 128
  float s = 0.f, s2 = 0.f;
  for (int row = blockIdx.x; row < M; row += gridDim.x) {
    float v = Z[(size_t)row * 128 + col];
    s += v;
    s2 += v * v;
  }
  atomicAdd(&stats[col], s);
  atomicAdd(&stats[128 + col], s2);
}

static __global__ void k_bn_finalize(const float* __restrict__ stats, int M,
                                     const float* __restrict__ g, const float* __restrict__ beta,
                                     float* __restrict__ ab) {
  int j = threadIdx.x;  // 128
  float m  = stats[j] / (float)M;
  float v  = stats[128 + j] / (float)M - m * m;
  float inv = rsqrtf(v + EPSV) * g[j];
  ab[j]       = inv;
  ab[128 + j] = beta[j] - m * inv;
}

template<bool OUT_BF16>
static __global__ void k_bn_apply(const float* __restrict__ Z, const float* __restrict__ ab,
                                  void* __restrict__ out, int n) {
  int i = blockIdx.x * blockDim.x + threadIdx.x;
  if (i < n) {
    int j = i & 127;
    float v = Z[i] * ab[j] + ab[128 + j];
    if constexpr (OUT_BF16) ((u16*)out)[i] = f2b(v);
    else                    ((float*)out)[i] = v;
  }
}

// ---------------- host-side layer driver ----------------

template<int K, bool AF32, bool OUT_BF16>
static void run_layer(const void* X,
                      const u16* Wt, const float* b,
                      const u16* fcWt, const float* fcb,
                      const float* g, const float* beta,
                      const int* off, const int* srt,
                      float* sOut, float* sIn, u16* Y, float* Z, u16* acc16,
                      float* stats, float* ab, void* out, hipStream_t stream)
{
  const int NT = (NN + 127) / 128;
  k_gemm_pipe<K, AF32><<<NT, 512, 0, stream>>>(X, Wt, sOut, Y, NN);

  k_gather<<<(NN + 3) / 4, 256, 0, stream>>>(off, srt, sIn, Y, b, acc16);

  k_fc_mfma<<<NT, 512, 0, stream>>>(acc16, fcWt, fcb, Z, NN);

  k_zero<<<1, 256, 0, stream>>>(stats, 256);
  k_bn_stats<<<1024, 128, 0, stream>>>(Z, NN, stats);
  k_bn_finalize<<<1, 128, 0, stream>>>(stats, NN, g, beta, ab);
  k_bn_apply<OUT_BF16><<<(NN * HID + 255) / 256, 256, 0, stream>>>(Z, ab, out, NN * HID);
}

extern "C" void kernel_launch(void* const* d_in, const int* in_sizes, int n_in,
                              void* d_out, int out_size, void* d_ws, size_t ws_size,
                              hipStream_t stream)
{
  const float* x    = (const float*)d_in[0];
  const int*   seq  = (const int*)d_in[1];
  const int*   knn  = (const int*)d_in[2];
  const int*   dis  = (const int*)d_in[3];
  const float* W0   = (const float*)d_in[4];
  const float* b0   = (const float*)d_in[5];
  const float* fcW0 = (const float*)d_in[6];
  const float* fcb0 = (const float*)d_in[7];
  const float* g0   = (const float*)d_in[8];
  const float* be0  = (const float*)d_in[9];
  const float* W1   = (const float*)d_in[10];
  const float* b1   = (const float*)d_in[11];
  const float* fcW1 = (const float*)d_in[12];
  const float* fcb1 = (const float*)d_in[13];
  const float* g1   = (const float*)d_in[14];
  const float* be1  = (const float*)d_in[15];

  const int E[3] = { in_sizes[1] / 2, in_sizes[2] / 2, in_sizes[3] / 2 };
  const int* srcs[3] = { seq, knn, dis };

  const size_t N = NN;
  const int M3 = 3 * NN;

  float* ws    = (float*)d_ws;
  float* sOut  = ws;                        // 3N
  float* sIn   = sOut + 3 * N;              // 3N
  u16*   acc16 = (u16*)(sIn + 3 * N);       // N*128 bf16 (in former acc f32 region)
  float* accF  = (float*)acc16;             // region size N*128 f32
  float* stats = accF + N * 128;            // 256
  float* ab    = stats + 256;               // 256
  u16*   Y     = (u16*)(ab + 256);          // N*384 bf16 (Z aliases: Y dead after gather)
  float* Z     = (float*)Y;                 // N*128 f32
  u16*   h16   = Y + N * 384;               // N*128 bf16
  u16*   Wt0   = h16 + N * 128;             // 3*128*1280
  u16*   Wt1   = Wt0 + 3 * 128 * 1280;      // 3*128*128
  u16*   fcWt0 = Wt1 + 3 * 128 * 128;       // 128*128
  u16*   fcWt1 = fcWt0 + 128 * 128;         // 128*128
  int*   counts= (int*)(fcWt1 + 128 * 128);
  int*   off   = counts + (M3 + 1);
  int*   aux   = off + (M3 + 1);
  int*   cur   = aux + 1536;
  int*   srt   = cur + M3;                  // ETOT ints

  // weight transpose+convert
  k_cvt_w<<<(3 * 1280 * 128 + 255) / 256, 256, 0, stream>>>(W0, Wt0, 1280);
  k_cvt_w<<<(3 * 128 * 128 + 255) / 256, 256, 0, stream>>>(W1, Wt1, 128);
  k_cvt_fcw<<<(128 * 128 + 255) / 256, 256, 0, stream>>>(fcW0, fcWt0);
  k_cvt_fcw<<<(128 * 128 + 255) / 256, 256, 0, stream>>>(fcW1, fcWt1);

  // degrees
  k_zero<<<(6 * NN + 255) / 256, 256, 0, stream>>>(sOut, 6 * NN);
  for (int r = 0; r < 3; ++r) {
    k_deg<<<(E[r] + 255) / 256, 256, 0, stream>>>(
        srcs[r], srcs[r] + E[r], E[r], sOut + (size_t)r * N, sIn + (size_t)r * N);
  }
  k_counts<<<(M3 + 1 + 255) / 256, 256, 0, stream>>>(sIn, counts, M3);
  k_rsqrt_clip<<<(6 * NN + 255) / 256, 256, 0, stream>>>(sOut, 6 * NN);

  // CSR: exclusive scan of counts[M3+1] -> off
  const int nsc = M3 + 1;
  const int nb  = (nsc + 255) / 256;
  k_scan1<<<nb, 256, 0, stream>>>(counts, off, aux, nsc);
  k_scan2<<<1, 256, 0, stream>>>(aux, nb);
  k_scan3<<<nb, 256, 0, stream>>>(off, aux, nsc);

  k_zero_i<<<(M3 + 255) / 256, 256, 0, stream>>>(cur, M3);
  for (int r = 0; r < 3; ++r) {
    k_fill<<<(E[r] + 255) / 256, 256, 0, stream>>>(
        srcs[r], srcs[r] + E[r], E[r], off, cur, r * NN, srt);
  }

  // layer 0: x f32 [N,1280] -> h16 bf16 [N,128]
  run_layer<1280, true, true>(x, Wt0, b0, fcWt0, fcb0, g0, be0, off, srt,
                              sOut, sIn, Y, Z, acc16, stats, ab, h16, stream);

  // layer 1: h16 bf16 [N,128] -> d_out f32 [N,128]
  run_layer<128, false, false>(h16, Wt1, b1, fcWt1, fcb1, g1, be1, off, srt,
                               sOut, sIn, Y, Z, acc16, stats, ab, d_out, stream);
}